// Round 20
// baseline (174.821 us; speedup 1.0000x reference)
//
#include <hip/hip_runtime.h>
#include <stdint.h>

typedef unsigned short u16;
typedef unsigned int u32;
typedef __attribute__((ext_vector_type(8))) short bf16x8;
typedef __attribute__((ext_vector_type(4))) float f32x4;
typedef __attribute__((ext_vector_type(16))) float f32x16;

// ---------- helpers ----------
__device__ __forceinline__ u16 f2bf(float f) {
  union { float f; unsigned u; } v; v.f = f;
  unsigned r = v.u + 0x7fffu + ((v.u >> 16) & 1u);  // round-to-nearest-even
  return (u16)(r >> 16);
}

__device__ __forceinline__ u32 pk_bf16(float lo, float hi) {
  u32 r;
  asm("v_cvt_pk_bf16_f32 %0, %1, %2" : "=v"(r) : "v"(lo), "v"(hi));
  return r;
}
#define PLSWAP(a, b) asm volatile("v_permlane32_swap_b32 %0, %1" : "+v"(a), "+v"(b))

__device__ __forceinline__ void async_copy16(u16* lds_dst, const u16* g_src) {
  __builtin_amdgcn_global_load_lds(
      (const __attribute__((address_space(1))) unsigned*)(g_src),
      (__attribute__((address_space(3))) unsigned*)(lds_dst),
      16, 0, 0);
}

#define MFMA16(a, b, c) __builtin_amdgcn_mfma_f32_16x16x32_bf16((a), (b), (c), 0, 0, 0)
#define MFMA32(a, b, c) __builtin_amdgcn_mfma_f32_32x32x16_bf16((a), (b), (c), 0, 0, 0)

// Q pre-scale: 1/sqrt(64) * log2(e)  (softmax via exp2)
#define QSCALE 0.18033688011112042f

// ---------- fused prep: wqkv transpose | wproj transpose | x cvt ----------
__global__ void prep_kernel(const float* __restrict__ x,
                            const float* __restrict__ wqkv,
                            const float* __restrict__ wproj,
                            u16* __restrict__ xbf,
                            u16* __restrict__ wqkvT,
                            u16* __restrict__ wprojT) {
  __shared__ float tile[32][33];
  const int bid = blockIdx.x;
  if (bid < 4096) {
    const float* in;
    u16* out;
    int R, C, bx, by;
    if (bid < 3072) {
      in = wqkv; out = wqkvT; R = 1024; C = 3072;
      bx = (bid % 96) * 32; by = (bid / 96) * 32;
    } else {
      in = wproj; out = wprojT; R = 1024; C = 1024;
      const int idx = bid - 3072;
      bx = (idx % 32) * 32; by = (idx / 32) * 32;
    }
    const int tx = threadIdx.x & 31, ty = threadIdx.x >> 5;
#pragma unroll
    for (int j = 0; j < 32; j += 8)
      tile[ty + j][tx] = in[(size_t)(by + ty + j) * C + bx + tx];
    __syncthreads();
#pragma unroll
    for (int j = 0; j < 32; j += 8)
      out[(size_t)(bx + ty + j) * R + by + tx] = f2bf(tile[tx][ty + j]);
  } else {
    const int n4 = (8192 * 1024) / 4;
    int i = (bid - 4096) * 256 + threadIdx.x;
    for (; i < n4; i += 2048 * 256) {
      float4 v = ((const float4*)x)[i];
      ushort4 o;
      o.x = f2bf(v.x); o.y = f2bf(v.y); o.z = f2bf(v.z); o.w = f2bf(v.w);
      ((ushort4*)xbf)[i] = o;
    }
  }
}

// ---------- counted-vmcnt dbuf 128x128 GEMM, BK=64 (frozen) ----------
// MODE 0: qkv scatter epilogue (q*QSCALE, k, vT bf16); MODE 1: f32 [M][N].
template<int MODE>
__global__ __launch_bounds__(256, 2)
void gemm_cnt(const u16* __restrict__ A, const u16* __restrict__ BT,
              int K, int N,
              u16* __restrict__ q_o, u16* __restrict__ k_o, u16* __restrict__ vt_o,
              float* __restrict__ f_o) {
  __shared__ u16 As[2][128 * 64];
  __shared__ u16 Bs[2][128 * 64];

  const int t = threadIdx.x;
  const int w = t >> 6, l = t & 63;
  const int lr = l & 15, g = l >> 4;
  const int wm = (w >> 1) * 64, wn = (w & 1) * 64;
  const int m0 = blockIdx.x * 128, n0 = blockIdx.y * 128;

  const int r = t >> 3;
  const int sw = ((t & 7) * 16) ^ ((r & 7) << 4);
  const u16* pA = A + (size_t)(m0 + r) * K + (sw >> 1);
  const u16* pB = BT + (size_t)(n0 + r) * K + (sw >> 1);

#define STG(buf, kk)                                                    \
  do {                                                                  \
    async_copy16(&As[buf][t * 8],        pA + (kk));                    \
    async_copy16(&As[buf][2048 + t * 8], pA + (size_t)32 * K + (kk));   \
    async_copy16(&As[buf][4096 + t * 8], pA + (size_t)64 * K + (kk));   \
    async_copy16(&As[buf][6144 + t * 8], pA + (size_t)96 * K + (kk));   \
    async_copy16(&Bs[buf][t * 8],        pB + (kk));                    \
    async_copy16(&Bs[buf][2048 + t * 8], pB + (size_t)32 * K + (kk));   \
    async_copy16(&Bs[buf][4096 + t * 8], pB + (size_t)64 * K + (kk));   \
    async_copy16(&Bs[buf][6144 + t * 8], pB + (size_t)96 * K + (kk));   \
  } while (0)

  f32x4 acc[4][4] = {};

  STG(0, 0);  // prologue: tile 0 in flight

  const int NTt = K / 64;
  for (int T = 0; T < NTt; ++T) {
    const int cur = T & 1;
    if (T + 1 < NTt) {
      STG(cur ^ 1, (T + 1) * 64);
      asm volatile("s_waitcnt vmcnt(8)" ::: "memory");  // tile T retired
    } else {
      asm volatile("s_waitcnt vmcnt(0)" ::: "memory");
    }
    __builtin_amdgcn_sched_barrier(0);
    asm volatile("s_barrier" ::: "memory");  // all waves' tile-T loads visible

    bf16x8 af[4][2], bfr[4][2];
#pragma unroll
    for (int mf = 0; mf < 4; ++mf)
#pragma unroll
      for (int ks = 0; ks < 2; ++ks) {
        const int row = wm + mf * 16 + lr;
        af[mf][ks] = *(const bf16x8*)&As[cur][row * 64 + (((ks * 64 + g * 16) ^ ((row & 7) << 4)) >> 1)];
      }
#pragma unroll
    for (int nf = 0; nf < 4; ++nf)
#pragma unroll
      for (int ks = 0; ks < 2; ++ks) {
        const int row = wn + nf * 16 + lr;
        bfr[nf][ks] = *(const bf16x8*)&Bs[cur][row * 64 + (((ks * 64 + g * 16) ^ ((row & 7) << 4)) >> 1)];
      }
#pragma unroll
    for (int mf = 0; mf < 4; ++mf)
#pragma unroll
      for (int nf = 0; nf < 4; ++nf) {
        acc[mf][nf] = MFMA16(af[mf][0], bfr[nf][0], acc[mf][nf]);
        acc[mf][nf] = MFMA16(af[mf][1], bfr[nf][1], acc[mf][nf]);
      }
    asm volatile("s_barrier" ::: "memory");  // reads(cur) done before overwrite
  }
#undef STG

  // ---- epilogue ----
#pragma unroll
  for (int mf = 0; mf < 4; ++mf) {
#pragma unroll
    for (int nf = 0; nf < 4; ++nf) {
      const int col = n0 + wn + nf * 16 + lr;
#pragma unroll
      for (int j = 0; j < 4; ++j) {
        const int rowc = m0 + wm + mf * 16 + g * 4 + j;
        const float v = acc[mf][nf][j];
        if (MODE == 0) {
          const int which = col >> 10, rr = col & 1023;
          const int h = rr >> 6, hd = rr & 63;
          const int b = rowc >> 11, s = rowc & 2047;
          const size_t bh = (size_t)b * 16 + h;
          if (which == 0)      q_o[(bh * 2048 + s) * 64 + hd] = f2bf(v * QSCALE);
          else if (which == 1) k_o[(bh * 2048 + s) * 64 + hd] = f2bf(v);
          else                 vt_o[(bh * 64 + hd) * 2048 + s] = f2bf(v);
        } else {
          f_o[(size_t)rowc * N + col] = v;
        }
      }
    }
  }
}

// ---------- flash attention (v5.1, best verified): 4-way lsum split ----------
// 1024 blocks = exactly 4/CU. Per tile: STAGE(ti+1) -> vmcnt(4) -> s_barrier
// -> compute(cur) -> s_barrier. Causal balance: qtile from bid>>6 via
// {15-a, 8+a, 4+a, 3-a} (every CU-class work sum = 34).
__global__ __launch_bounds__(256, 4)
void attn_kernel(const u16* __restrict__ qws, const u16* __restrict__ kws,
                 const u16* __restrict__ vtws, u16* __restrict__ ybf) {
  __shared__ u16 Ksh[2][64 * 64];   // [key][hd], swizzled
  __shared__ u16 VTsh[2][64 * 64];  // [hd][key], swizzled

  const int bh = blockIdx.x & 63;
  const int gq = blockIdx.x >> 6, a2 = gq & 3, b2 = gq >> 2;
  const int qtile = (b2 == 0) ? 15 - a2 : (b2 == 1) ? 8 + a2 : (b2 == 2) ? 4 + a2 : 3 - a2;
  const int t = threadIdx.x;
  const int w = t >> 6, l = t & 63;
  const int lq = l & 31;
  const int h = l >> 5;
  const int q0 = qtile * 128 + w * 32;
  const int qg = q0 + lq;

  bf16x8 qf[4];
  {
    const u16* qb = qws + ((size_t)bh * 2048 + qg) * 64 + h * 8;
#pragma unroll
    for (int s = 0; s < 4; ++s) qf[s] = *(const bf16x8*)(qb + s * 16);
  }

  f32x16 oacc[2] = {};
  f32x4 lsv = {};  // 4-way split lsum (breaks the 32-deep serial add chain)

  const int srow = t >> 3;
  const int ssw = ((t & 7) * 16) ^ ((srow & 7) << 4);
  const u16* kb0 = kws + ((size_t)bh * 2048 + srow) * 64 + (ssw >> 1);
  const u16* vb0 = vtws + ((size_t)bh * 64 + srow) * 2048 + (ssw >> 1);

#define STAGE(kv0, buf)                                                \
  do {                                                                 \
    async_copy16(&Ksh[buf][t * 8],          kb0 + (size_t)(kv0)*64);   \
    async_copy16(&Ksh[buf][(t + 256) * 8],  kb0 + (size_t)((kv0)+32)*64); \
    async_copy16(&VTsh[buf][t * 8],         vb0 + (kv0));              \
    async_copy16(&VTsh[buf][(t + 256) * 8], vb0 + (size_t)32*2048 + (kv0)); \
  } while (0)

  const int nt = (qtile + 1) * 2;
  STAGE(0, 0);

  for (int ti = 0; ti < nt; ++ti) {
    const int kv0 = ti * 64;
    const int cur = ti & 1;
    if (ti + 1 < nt) {
      STAGE((ti + 1) * 64, cur ^ 1);
      asm volatile("s_waitcnt vmcnt(4)" ::: "memory");  // tile ti retired
    } else {
      asm volatile("s_waitcnt vmcnt(0)" ::: "memory");
    }
    __builtin_amdgcn_sched_barrier(0);
    asm volatile("s_barrier" ::: "memory");  // tile ti visible to all waves

    if (kv0 <= q0 + 31) {
      const u16* Kc = Ksh[cur];
      const u16* Vc = VTsh[cur];

      f32x16 st[2] = {};
      __builtin_amdgcn_s_setprio(1);
#pragma unroll
      for (int kt = 0; kt < 2; ++kt) {
        const int krow = kt * 32 + lq;
        const int swz = (krow & 7) << 4;
#pragma unroll
        for (int s = 0; s < 4; ++s) {
          bf16x8 kf = *(const bf16x8*)&Kc[krow * 64 + (((s * 32 + h * 16) ^ swz) >> 1)];
          st[kt] = MFMA32(kf, qf[s], st[kt]);
        }
      }
      __builtin_amdgcn_s_setprio(0);

      const bool diag = (kv0 + 63 > q0);
#pragma unroll
      for (int kt = 0; kt < 2; ++kt)
#pragma unroll
        for (int p = 0; p < 16; ++p) {
          float e = exp2f(st[kt][p]);  // Q pre-scaled by 0.125*log2e
          if (diag) {
            const int key = kv0 + kt * 32 + (p & 3) + 8 * (p >> 2) + 4 * h;
            e = (key <= qg) ? e : 0.f;
          }
          st[kt][p] = e;
          lsv[p & 3] += e;  // static index (p compile-time) -> register
        }

      bf16x8 pb[4];
#pragma unroll
      for (int kt = 0; kt < 2; ++kt)
#pragma unroll
        for (int s2l = 0; s2l < 2; ++s2l) {
          const int p0 = s2l * 8;
          u32 L0 = pk_bf16(st[kt][p0 + 0], st[kt][p0 + 1]);
          u32 L1 = pk_bf16(st[kt][p0 + 2], st[kt][p0 + 3]);
          u32 H0 = pk_bf16(st[kt][p0 + 4], st[kt][p0 + 5]);
          u32 H1 = pk_bf16(st[kt][p0 + 6], st[kt][p0 + 7]);
          PLSWAP(L0, H0);
          PLSWAP(L1, H1);
          union { u32 u[4]; bf16x8 v; } pw;
          pw.u[0] = L0; pw.u[1] = L1; pw.u[2] = H0; pw.u[3] = H1;
          pb[kt * 2 + s2l] = pw.v;
        }

      __builtin_amdgcn_s_setprio(1);
#pragma unroll
      for (int dt = 0; dt < 2; ++dt) {
        const int vrow = dt * 32 + lq;
        const int swz = (vrow & 7) << 4;
#pragma unroll
        for (int s2 = 0; s2 < 4; ++s2) {
          bf16x8 vf = *(const bf16x8*)&Vc[vrow * 64 + (((s2 * 32 + h * 16) ^ swz) >> 1)];
          oacc[dt] = MFMA32(vf, pb[s2], oacc[dt]);
        }
      }
      __builtin_amdgcn_s_setprio(0);
    }
    asm volatile("s_barrier" ::: "memory");  // reads(cur) done before overwrite
  }
#undef STAGE

  float lsum = (lsv[0] + lsv[1]) + (lsv[2] + lsv[3]);
  lsum += __shfl_xor(lsum, 32, 64);
  const float linv = 1.f / lsum;

  const int b = bh >> 4, hh = bh & 15;
  u16* yb = ybf + ((size_t)b * 2048 + qg) * 1024 + hh * 64;
#pragma unroll
  for (int dt = 0; dt < 2; ++dt)
#pragma unroll
    for (int pg = 0; pg < 4; ++pg) {
      u32 w0 = pk_bf16(oacc[dt][pg * 4 + 0] * linv, oacc[dt][pg * 4 + 1] * linv);
      u32 w1 = pk_bf16(oacc[dt][pg * 4 + 2] * linv, oacc[dt][pg * 4 + 3] * linv);
      union { u32 u[2]; unsigned long long ll; } pk2;
      pk2.u[0] = w0; pk2.u[1] = w1;
      *(unsigned long long*)(yb + dt * 32 + 8 * pg + 4 * h) = pk2.ll;
    }
}

// ---------- launch ----------
extern "C" void kernel_launch(void* const* d_in, const int* in_sizes, int n_in,
                              void* d_out, int out_size, void* d_ws, size_t ws_size,
                              hipStream_t stream) {
  const float* x     = (const float*)d_in[0];   // [4,2048,1024]
  const float* wqkv  = (const float*)d_in[1];   // [1024,3072]
  const float* wproj = (const float*)d_in[2];   // [1024,1024]
  float* out = (float*)d_out;                   // [4,2048,1024] f32

  char* ws = (char*)d_ws;
  u16* xbf    = (u16*)ws;
  u16* ybf    = xbf;  // alias (x dead after qkv GEMM)
  u16* wqkvT  = (u16*)(ws + 16777216);
  u16* wprojT = (u16*)(ws + 16777216 + 6291456);
  u16* qws    = (u16*)(ws + 25165824);
  u16* kws    = (u16*)(ws + 41943040);
  u16* vtws   = (u16*)(ws + 58720256);

  prep_kernel<<<6144, 256, 0, stream>>>(x, wqkv, wproj, xbf, wqkvT, wprojT);
  gemm_cnt<0><<<dim3(64, 24), 256, 0, stream>>>(xbf, wqkvT, 1024, 3072, qws, kws, vtws, nullptr);
  attn_kernel<<<16 * 64, 256, 0, stream>>>(qws, kws, vtws, ybf);
  gemm_cnt<1><<<dim3(64, 8), 256, 0, stream>>>(ybf, wprojT, 1024, 1024, nullptr, nullptr, nullptr, out);
}

// Round 21
// 174.663 us; speedup vs baseline: 1.0009x; 1.0009x over previous
//
#include <hip/hip_runtime.h>
#include <stdint.h>

typedef unsigned short u16;
typedef unsigned int u32;
typedef __attribute__((ext_vector_type(8))) short bf16x8;
typedef __attribute__((ext_vector_type(4))) float f32x4;
typedef __attribute__((ext_vector_type(16))) float f32x16;

// ---------- helpers ----------
__device__ __forceinline__ u16 f2bf(float f) {
  union { float f; unsigned u; } v; v.f = f;
  unsigned r = v.u + 0x7fffu + ((v.u >> 16) & 1u);  // round-to-nearest-even
  return (u16)(r >> 16);
}

__device__ __forceinline__ u32 pk_bf16(float lo, float hi) {
  u32 r;
  asm("v_cvt_pk_bf16_f32 %0, %1, %2" : "=v"(r) : "v"(lo), "v"(hi));
  return r;
}
#define PLSWAP(a, b) asm volatile("v_permlane32_swap_b32 %0, %1" : "+v"(a), "+v"(b))

__device__ __forceinline__ void async_copy16(u16* lds_dst, const u16* g_src) {
  __builtin_amdgcn_global_load_lds(
      (const __attribute__((address_space(1))) unsigned*)(g_src),
      (__attribute__((address_space(3))) unsigned*)(lds_dst),
      16, 0, 0);
}

#define MFMA16(a, b, c) __builtin_amdgcn_mfma_f32_16x16x32_bf16((a), (b), (c), 0, 0, 0)
#define MFMA32(a, b, c) __builtin_amdgcn_mfma_f32_32x32x16_bf16((a), (b), (c), 0, 0, 0)

// Q pre-scale: 1/sqrt(64) * log2(e)  (softmax via exp2)
#define QSCALE 0.18033688011112042f

// ---------- fused prep: wqkv transpose | wproj transpose | x cvt ----------
__global__ void prep_kernel(const float* __restrict__ x,
                            const float* __restrict__ wqkv,
                            const float* __restrict__ wproj,
                            u16* __restrict__ xbf,
                            u16* __restrict__ wqkvT,
                            u16* __restrict__ wprojT) {
  __shared__ float tile[32][33];
  const int bid = blockIdx.x;
  if (bid < 4096) {
    const float* in;
    u16* out;
    int R, C, bx, by;
    if (bid < 3072) {
      in = wqkv; out = wqkvT; R = 1024; C = 3072;
      bx = (bid % 96) * 32; by = (bid / 96) * 32;
    } else {
      in = wproj; out = wprojT; R = 1024; C = 1024;
      const int idx = bid - 3072;
      bx = (idx % 32) * 32; by = (idx / 32) * 32;
    }
    const int tx = threadIdx.x & 31, ty = threadIdx.x >> 5;
#pragma unroll
    for (int j = 0; j < 32; j += 8)
      tile[ty + j][tx] = in[(size_t)(by + ty + j) * C + bx + tx];
    __syncthreads();
#pragma unroll
    for (int j = 0; j < 32; j += 8)
      out[(size_t)(bx + ty + j) * R + by + tx] = f2bf(tile[tx][ty + j]);
  } else {
    const int n4 = (8192 * 1024) / 4;
    int i = (bid - 4096) * 256 + threadIdx.x;
    for (; i < n4; i += 2048 * 256) {
      float4 v = ((const float4*)x)[i];
      ushort4 o;
      o.x = f2bf(v.x); o.y = f2bf(v.y); o.z = f2bf(v.z); o.w = f2bf(v.w);
      ((ushort4*)xbf)[i] = o;
    }
  }
}

// ---------- counted-vmcnt dbuf 128x128 GEMM, BK=64 (frozen) ----------
// MODE 0: qkv scatter epilogue (q*QSCALE, k, vT bf16); MODE 1: f32 [M][N].
template<int MODE>
__global__ __launch_bounds__(256, 2)
void gemm_cnt(const u16* __restrict__ A, const u16* __restrict__ BT,
              int K, int N,
              u16* __restrict__ q_o, u16* __restrict__ k_o, u16* __restrict__ vt_o,
              float* __restrict__ f_o) {
  __shared__ u16 As[2][128 * 64];
  __shared__ u16 Bs[2][128 * 64];

  const int t = threadIdx.x;
  const int w = t >> 6, l = t & 63;
  const int lr = l & 15, g = l >> 4;
  const int wm = (w >> 1) * 64, wn = (w & 1) * 64;
  const int m0 = blockIdx.x * 128, n0 = blockIdx.y * 128;

  const int r = t >> 3;
  const int sw = ((t & 7) * 16) ^ ((r & 7) << 4);
  const u16* pA = A + (size_t)(m0 + r) * K + (sw >> 1);
  const u16* pB = BT + (size_t)(n0 + r) * K + (sw >> 1);

#define STG(buf, kk)                                                    \
  do {                                                                  \
    async_copy16(&As[buf][t * 8],        pA + (kk));                    \
    async_copy16(&As[buf][2048 + t * 8], pA + (size_t)32 * K + (kk));   \
    async_copy16(&As[buf][4096 + t * 8], pA + (size_t)64 * K + (kk));   \
    async_copy16(&As[buf][6144 + t * 8], pA + (size_t)96 * K + (kk));   \
    async_copy16(&Bs[buf][t * 8],        pB + (kk));                    \
    async_copy16(&Bs[buf][2048 + t * 8], pB + (size_t)32 * K + (kk));   \
    async_copy16(&Bs[buf][4096 + t * 8], pB + (size_t)64 * K + (kk));   \
    async_copy16(&Bs[buf][6144 + t * 8], pB + (size_t)96 * K + (kk));   \
  } while (0)

  f32x4 acc[4][4] = {};

  STG(0, 0);  // prologue: tile 0 in flight

  const int NTt = K / 64;
  for (int T = 0; T < NTt; ++T) {
    const int cur = T & 1;
    if (T + 1 < NTt) {
      STG(cur ^ 1, (T + 1) * 64);
      asm volatile("s_waitcnt vmcnt(8)" ::: "memory");  // tile T retired
    } else {
      asm volatile("s_waitcnt vmcnt(0)" ::: "memory");
    }
    __builtin_amdgcn_sched_barrier(0);
    asm volatile("s_barrier" ::: "memory");  // all waves' tile-T loads visible

    bf16x8 af[4][2], bfr[4][2];
#pragma unroll
    for (int mf = 0; mf < 4; ++mf)
#pragma unroll
      for (int ks = 0; ks < 2; ++ks) {
        const int row = wm + mf * 16 + lr;
        af[mf][ks] = *(const bf16x8*)&As[cur][row * 64 + (((ks * 64 + g * 16) ^ ((row & 7) << 4)) >> 1)];
      }
#pragma unroll
    for (int nf = 0; nf < 4; ++nf)
#pragma unroll
      for (int ks = 0; ks < 2; ++ks) {
        const int row = wn + nf * 16 + lr;
        bfr[nf][ks] = *(const bf16x8*)&Bs[cur][row * 64 + (((ks * 64 + g * 16) ^ ((row & 7) << 4)) >> 1)];
      }
#pragma unroll
    for (int mf = 0; mf < 4; ++mf)
#pragma unroll
      for (int nf = 0; nf < 4; ++nf) {
        acc[mf][nf] = MFMA16(af[mf][0], bfr[nf][0], acc[mf][nf]);
        acc[mf][nf] = MFMA16(af[mf][1], bfr[nf][1], acc[mf][nf]);
      }
    asm volatile("s_barrier" ::: "memory");  // reads(cur) done before overwrite
  }
#undef STG

  // ---- epilogue ----
#pragma unroll
  for (int mf = 0; mf < 4; ++mf) {
#pragma unroll
    for (int nf = 0; nf < 4; ++nf) {
      const int col = n0 + wn + nf * 16 + lr;
#pragma unroll
      for (int j = 0; j < 4; ++j) {
        const int rowc = m0 + wm + mf * 16 + g * 4 + j;
        const float v = acc[mf][nf][j];
        if (MODE == 0) {
          const int which = col >> 10, rr = col & 1023;
          const int h = rr >> 6, hd = rr & 63;
          const int b = rowc >> 11, s = rowc & 2047;
          const size_t bh = (size_t)b * 16 + h;
          if (which == 0)      q_o[(bh * 2048 + s) * 64 + hd] = f2bf(v * QSCALE);
          else if (which == 1) k_o[(bh * 2048 + s) * 64 + hd] = f2bf(v);
          else                 vt_o[(bh * 64 + hd) * 2048 + s] = f2bf(v);
        } else {
          f_o[(size_t)rowc * N + col] = v;
        }
      }
    }
  }
}

// ---------- flash attention (v5.1, best verified): 4-way lsum split ----------
// 1024 blocks = exactly 4/CU. Per tile: STAGE(ti+1) -> vmcnt(4) -> s_barrier
// -> compute(cur) -> s_barrier. Causal balance: qtile from bid>>6 via
// {15-a, 8+a, 4+a, 3-a} (every CU-class work sum = 34).
__global__ __launch_bounds__(256, 4)
void attn_kernel(const u16* __restrict__ qws, const u16* __restrict__ kws,
                 const u16* __restrict__ vtws, u16* __restrict__ ybf) {
  __shared__ u16 Ksh[2][64 * 64];   // [key][hd], swizzled
  __shared__ u16 VTsh[2][64 * 64];  // [hd][key], swizzled

  const int bh = blockIdx.x & 63;
  const int gq = blockIdx.x >> 6, a2 = gq & 3, b2 = gq >> 2;
  const int qtile = (b2 == 0) ? 15 - a2 : (b2 == 1) ? 8 + a2 : (b2 == 2) ? 4 + a2 : 3 - a2;
  const int t = threadIdx.x;
  const int w = t >> 6, l = t & 63;
  const int lq = l & 31;
  const int h = l >> 5;
  const int q0 = qtile * 128 + w * 32;
  const int qg = q0 + lq;

  bf16x8 qf[4];
  {
    const u16* qb = qws + ((size_t)bh * 2048 + qg) * 64 + h * 8;
#pragma unroll
    for (int s = 0; s < 4; ++s) qf[s] = *(const bf16x8*)(qb + s * 16);
  }

  f32x16 oacc[2] = {};
  f32x4 lsv = {};  // 4-way split lsum (breaks the 32-deep serial add chain)

  const int srow = t >> 3;
  const int ssw = ((t & 7) * 16) ^ ((srow & 7) << 4);
  const u16* kb0 = kws + ((size_t)bh * 2048 + srow) * 64 + (ssw >> 1);
  const u16* vb0 = vtws + ((size_t)bh * 64 + srow) * 2048 + (ssw >> 1);

#define STAGE(kv0, buf)                                                \
  do {                                                                 \
    async_copy16(&Ksh[buf][t * 8],          kb0 + (size_t)(kv0)*64);   \
    async_copy16(&Ksh[buf][(t + 256) * 8],  kb0 + (size_t)((kv0)+32)*64); \
    async_copy16(&VTsh[buf][t * 8],         vb0 + (kv0));              \
    async_copy16(&VTsh[buf][(t + 256) * 8], vb0 + (size_t)32*2048 + (kv0)); \
  } while (0)

  const int nt = (qtile + 1) * 2;
  STAGE(0, 0);

  for (int ti = 0; ti < nt; ++ti) {
    const int kv0 = ti * 64;
    const int cur = ti & 1;
    if (ti + 1 < nt) {
      STAGE((ti + 1) * 64, cur ^ 1);
      asm volatile("s_waitcnt vmcnt(4)" ::: "memory");  // tile ti retired
    } else {
      asm volatile("s_waitcnt vmcnt(0)" ::: "memory");
    }
    __builtin_amdgcn_sched_barrier(0);
    asm volatile("s_barrier" ::: "memory");  // tile ti visible to all waves

    if (kv0 <= q0 + 31) {
      const u16* Kc = Ksh[cur];
      const u16* Vc = VTsh[cur];

      f32x16 st[2] = {};
      __builtin_amdgcn_s_setprio(1);
#pragma unroll
      for (int kt = 0; kt < 2; ++kt) {
        const int krow = kt * 32 + lq;
        const int swz = (krow & 7) << 4;
#pragma unroll
        for (int s = 0; s < 4; ++s) {
          bf16x8 kf = *(const bf16x8*)&Kc[krow * 64 + (((s * 32 + h * 16) ^ swz) >> 1)];
          st[kt] = MFMA32(kf, qf[s], st[kt]);
        }
      }
      __builtin_amdgcn_s_setprio(0);

      const bool diag = (kv0 + 63 > q0);
#pragma unroll
      for (int kt = 0; kt < 2; ++kt)
#pragma unroll
        for (int p = 0; p < 16; ++p) {
          float e = exp2f(st[kt][p]);  // Q pre-scaled by 0.125*log2e
          if (diag) {
            const int key = kv0 + kt * 32 + (p & 3) + 8 * (p >> 2) + 4 * h;
            e = (key <= qg) ? e : 0.f;
          }
          st[kt][p] = e;
          lsv[p & 3] += e;  // static index (p compile-time) -> register
        }

      bf16x8 pb[4];
#pragma unroll
      for (int kt = 0; kt < 2; ++kt)
#pragma unroll
        for (int s2l = 0; s2l < 2; ++s2l) {
          const int p0 = s2l * 8;
          u32 L0 = pk_bf16(st[kt][p0 + 0], st[kt][p0 + 1]);
          u32 L1 = pk_bf16(st[kt][p0 + 2], st[kt][p0 + 3]);
          u32 H0 = pk_bf16(st[kt][p0 + 4], st[kt][p0 + 5]);
          u32 H1 = pk_bf16(st[kt][p0 + 6], st[kt][p0 + 7]);
          PLSWAP(L0, H0);
          PLSWAP(L1, H1);
          union { u32 u[4]; bf16x8 v; } pw;
          pw.u[0] = L0; pw.u[1] = L1; pw.u[2] = H0; pw.u[3] = H1;
          pb[kt * 2 + s2l] = pw.v;
        }

      __builtin_amdgcn_s_setprio(1);
#pragma unroll
      for (int dt = 0; dt < 2; ++dt) {
        const int vrow = dt * 32 + lq;
        const int swz = (vrow & 7) << 4;
#pragma unroll
        for (int s2 = 0; s2 < 4; ++s2) {
          bf16x8 vf = *(const bf16x8*)&Vc[vrow * 64 + (((s2 * 32 + h * 16) ^ swz) >> 1)];
          oacc[dt] = MFMA32(vf, pb[s2], oacc[dt]);
        }
      }
      __builtin_amdgcn_s_setprio(0);
    }
    asm volatile("s_barrier" ::: "memory");  // reads(cur) done before overwrite
  }
#undef STAGE

  float lsum = (lsv[0] + lsv[1]) + (lsv[2] + lsv[3]);
  lsum += __shfl_xor(lsum, 32, 64);
  const float linv = 1.f / lsum;

  const int b = bh >> 4, hh = bh & 15;
  u16* yb = ybf + ((size_t)b * 2048 + qg) * 1024 + hh * 64;
#pragma unroll
  for (int dt = 0; dt < 2; ++dt)
#pragma unroll
    for (int pg = 0; pg < 4; ++pg) {
      u32 w0 = pk_bf16(oacc[dt][pg * 4 + 0] * linv, oacc[dt][pg * 4 + 1] * linv);
      u32 w1 = pk_bf16(oacc[dt][pg * 4 + 2] * linv, oacc[dt][pg * 4 + 3] * linv);
      union { u32 u[2]; unsigned long long ll; } pk2;
      pk2.u[0] = w0; pk2.u[1] = w1;
      *(unsigned long long*)(yb + dt * 32 + 8 * pg + 4 * h) = pk2.ll;
    }
}

// ---------- launch ----------
extern "C" void kernel_launch(void* const* d_in, const int* in_sizes, int n_in,
                              void* d_out, int out_size, void* d_ws, size_t ws_size,
                              hipStream_t stream) {
  const float* x     = (const float*)d_in[0];   // [4,2048,1024]
  const float* wqkv  = (const float*)d_in[1];   // [1024,3072]
  const float* wproj = (const float*)d_in[2];   // [1024,1024]
  float* out = (float*)d_out;                   // [4,2048,1024] f32

  char* ws = (char*)d_ws;
  u16* xbf    = (u16*)ws;
  u16* ybf    = xbf;  // alias (x dead after qkv GEMM)
  u16* wqkvT  = (u16*)(ws + 16777216);
  u16* wprojT = (u16*)(ws + 16777216 + 6291456);
  u16* qws    = (u16*)(ws + 25165824);
  u16* kws    = (u16*)(ws + 41943040);
  u16* vtws   = (u16*)(ws + 58720256);

  prep_kernel<<<6144, 256, 0, stream>>>(x, wqkv, wproj, xbf, wqkvT, wprojT);
  gemm_cnt<0><<<dim3(64, 24), 256, 0, stream>>>(xbf, wqkvT, 1024, 3072, qws, kws, vtws, nullptr);
  attn_kernel<<<16 * 64, 256, 0, stream>>>(qws, kws, vtws, ybf);
  gemm_cnt<1><<<dim3(64, 8), 256, 0, stream>>>(ybf, wprojT, 1024, 1024, nullptr, nullptr, nullptr, out);
}

// Round 22
// 173.775 us; speedup vs baseline: 1.0060x; 1.0051x over previous
//
#include <hip/hip_runtime.h>
#include <stdint.h>

typedef unsigned short u16;
typedef unsigned int u32;
typedef __attribute__((ext_vector_type(8))) short bf16x8;
typedef __attribute__((ext_vector_type(4))) float f32x4;
typedef __attribute__((ext_vector_type(16))) float f32x16;

// ---------- helpers ----------
__device__ __forceinline__ u16 f2bf(float f) {
  union { float f; unsigned u; } v; v.f = f;
  unsigned r = v.u + 0x7fffu + ((v.u >> 16) & 1u);  // round-to-nearest-even
  return (u16)(r >> 16);
}

__device__ __forceinline__ u32 pk_bf16(float lo, float hi) {
  u32 r;
  asm("v_cvt_pk_bf16_f32 %0, %1, %2" : "=v"(r) : "v"(lo), "v"(hi));
  return r;
}
#define PLSWAP(a, b) asm volatile("v_permlane32_swap_b32 %0, %1" : "+v"(a), "+v"(b))

__device__ __forceinline__ void async_copy16(u16* lds_dst, const u16* g_src) {
  __builtin_amdgcn_global_load_lds(
      (const __attribute__((address_space(1))) unsigned*)(g_src),
      (__attribute__((address_space(3))) unsigned*)(lds_dst),
      16, 0, 0);
}

#define MFMA16(a, b, c) __builtin_amdgcn_mfma_f32_16x16x32_bf16((a), (b), (c), 0, 0, 0)
#define MFMA32(a, b, c) __builtin_amdgcn_mfma_f32_32x32x16_bf16((a), (b), (c), 0, 0, 0)

// Q pre-scale: 1/sqrt(64) * log2(e)  (softmax via exp2)
#define QSCALE 0.18033688011112042f

// ---------- fused prep: wqkv transpose | wproj transpose | x cvt ----------
__global__ void prep_kernel(const float* __restrict__ x,
                            const float* __restrict__ wqkv,
                            const float* __restrict__ wproj,
                            u16* __restrict__ xbf,
                            u16* __restrict__ wqkvT,
                            u16* __restrict__ wprojT) {
  __shared__ float tile[32][33];
  const int bid = blockIdx.x;
  if (bid < 4096) {
    const float* in;
    u16* out;
    int R, C, bx, by;
    if (bid < 3072) {
      in = wqkv; out = wqkvT; R = 1024; C = 3072;
      bx = (bid % 96) * 32; by = (bid / 96) * 32;
    } else {
      in = wproj; out = wprojT; R = 1024; C = 1024;
      const int idx = bid - 3072;
      bx = (idx % 32) * 32; by = (idx / 32) * 32;
    }
    const int tx = threadIdx.x & 31, ty = threadIdx.x >> 5;
#pragma unroll
    for (int j = 0; j < 32; j += 8)
      tile[ty + j][tx] = in[(size_t)(by + ty + j) * C + bx + tx];
    __syncthreads();
#pragma unroll
    for (int j = 0; j < 32; j += 8)
      out[(size_t)(bx + ty + j) * R + by + tx] = f2bf(tile[tx][ty + j]);
  } else {
    const int n4 = (8192 * 1024) / 4;
    int i = (bid - 4096) * 256 + threadIdx.x;
    for (; i < n4; i += 2048 * 256) {
      float4 v = ((const float4*)x)[i];
      ushort4 o;
      o.x = f2bf(v.x); o.y = f2bf(v.y); o.z = f2bf(v.z); o.w = f2bf(v.w);
      ((ushort4*)xbf)[i] = o;
    }
  }
}

// ---------- counted-vmcnt dbuf 128x128 GEMM, BK=64 (frozen) ----------
// MODE 0: qkv scatter epilogue (q*QSCALE, k, vT bf16); MODE 1: f32 [M][N].
template<int MODE>
__global__ __launch_bounds__(256, 2)
void gemm_cnt(const u16* __restrict__ A, const u16* __restrict__ BT,
              int K, int N,
              u16* __restrict__ q_o, u16* __restrict__ k_o, u16* __restrict__ vt_o,
              float* __restrict__ f_o) {
  __shared__ u16 As[2][128 * 64];
  __shared__ u16 Bs[2][128 * 64];

  const int t = threadIdx.x;
  const int w = t >> 6, l = t & 63;
  const int lr = l & 15, g = l >> 4;
  const int wm = (w >> 1) * 64, wn = (w & 1) * 64;
  const int m0 = blockIdx.x * 128, n0 = blockIdx.y * 128;

  const int r = t >> 3;
  const int sw = ((t & 7) * 16) ^ ((r & 7) << 4);
  const u16* pA = A + (size_t)(m0 + r) * K + (sw >> 1);
  const u16* pB = BT + (size_t)(n0 + r) * K + (sw >> 1);

#define STG(buf, kk)                                                    \
  do {                                                                  \
    async_copy16(&As[buf][t * 8],        pA + (kk));                    \
    async_copy16(&As[buf][2048 + t * 8], pA + (size_t)32 * K + (kk));   \
    async_copy16(&As[buf][4096 + t * 8], pA + (size_t)64 * K + (kk));   \
    async_copy16(&As[buf][6144 + t * 8], pA + (size_t)96 * K + (kk));   \
    async_copy16(&Bs[buf][t * 8],        pB + (kk));                    \
    async_copy16(&Bs[buf][2048 + t * 8], pB + (size_t)32 * K + (kk));   \
    async_copy16(&Bs[buf][4096 + t * 8], pB + (size_t)64 * K + (kk));   \
    async_copy16(&Bs[buf][6144 + t * 8], pB + (size_t)96 * K + (kk));   \
  } while (0)

  f32x4 acc[4][4] = {};

  STG(0, 0);  // prologue: tile 0 in flight

  const int NTt = K / 64;
  for (int T = 0; T < NTt; ++T) {
    const int cur = T & 1;
    if (T + 1 < NTt) {
      STG(cur ^ 1, (T + 1) * 64);
      asm volatile("s_waitcnt vmcnt(8)" ::: "memory");  // tile T retired
    } else {
      asm volatile("s_waitcnt vmcnt(0)" ::: "memory");
    }
    __builtin_amdgcn_sched_barrier(0);
    asm volatile("s_barrier" ::: "memory");  // all waves' tile-T loads visible

    bf16x8 af[4][2], bfr[4][2];
#pragma unroll
    for (int mf = 0; mf < 4; ++mf)
#pragma unroll
      for (int ks = 0; ks < 2; ++ks) {
        const int row = wm + mf * 16 + lr;
        af[mf][ks] = *(const bf16x8*)&As[cur][row * 64 + (((ks * 64 + g * 16) ^ ((row & 7) << 4)) >> 1)];
      }
#pragma unroll
    for (int nf = 0; nf < 4; ++nf)
#pragma unroll
      for (int ks = 0; ks < 2; ++ks) {
        const int row = wn + nf * 16 + lr;
        bfr[nf][ks] = *(const bf16x8*)&Bs[cur][row * 64 + (((ks * 64 + g * 16) ^ ((row & 7) << 4)) >> 1)];
      }
#pragma unroll
    for (int mf = 0; mf < 4; ++mf)
#pragma unroll
      for (int nf = 0; nf < 4; ++nf) {
        acc[mf][nf] = MFMA16(af[mf][0], bfr[nf][0], acc[mf][nf]);
        acc[mf][nf] = MFMA16(af[mf][1], bfr[nf][1], acc[mf][nf]);
      }
    asm volatile("s_barrier" ::: "memory");  // reads(cur) done before overwrite
  }
#undef STG

  // ---- epilogue ----
#pragma unroll
  for (int mf = 0; mf < 4; ++mf) {
#pragma unroll
    for (int nf = 0; nf < 4; ++nf) {
      const int col = n0 + wn + nf * 16 + lr;
#pragma unroll
      for (int j = 0; j < 4; ++j) {
        const int rowc = m0 + wm + mf * 16 + g * 4 + j;
        const float v = acc[mf][nf][j];
        if (MODE == 0) {
          const int which = col >> 10, rr = col & 1023;
          const int h = rr >> 6, hd = rr & 63;
          const int b = rowc >> 11, s = rowc & 2047;
          const size_t bh = (size_t)b * 16 + h;
          if (which == 0)      q_o[(bh * 2048 + s) * 64 + hd] = f2bf(v * QSCALE);
          else if (which == 1) k_o[(bh * 2048 + s) * 64 + hd] = f2bf(v);
          else                 vt_o[(bh * 64 + hd) * 2048 + s] = f2bf(v);
        } else {
          f_o[(size_t)rowc * N + col] = v;
        }
      }
    }
  }
}

// ---------- flash attention (v5.1, best verified): 4-way lsum split ----------
// 1024 blocks = exactly 4/CU. Per tile: STAGE(ti+1) -> vmcnt(4) -> s_barrier
// -> compute(cur) -> s_barrier. Causal balance: qtile from bid>>6 via
// {15-a, 8+a, 4+a, 3-a} (every CU-class work sum = 34).
__global__ __launch_bounds__(256, 4)
void attn_kernel(const u16* __restrict__ qws, const u16* __restrict__ kws,
                 const u16* __restrict__ vtws, u16* __restrict__ ybf) {
  __shared__ u16 Ksh[2][64 * 64];   // [key][hd], swizzled
  __shared__ u16 VTsh[2][64 * 64];  // [hd][key], swizzled

  const int bh = blockIdx.x & 63;
  const int gq = blockIdx.x >> 6, a2 = gq & 3, b2 = gq >> 2;
  const int qtile = (b2 == 0) ? 15 - a2 : (b2 == 1) ? 8 + a2 : (b2 == 2) ? 4 + a2 : 3 - a2;
  const int t = threadIdx.x;
  const int w = t >> 6, l = t & 63;
  const int lq = l & 31;
  const int h = l >> 5;
  const int q0 = qtile * 128 + w * 32;
  const int qg = q0 + lq;

  bf16x8 qf[4];
  {
    const u16* qb = qws + ((size_t)bh * 2048 + qg) * 64 + h * 8;
#pragma unroll
    for (int s = 0; s < 4; ++s) qf[s] = *(const bf16x8*)(qb + s * 16);
  }

  f32x16 oacc[2] = {};
  f32x4 lsv = {};  // 4-way split lsum (breaks the 32-deep serial add chain)

  const int srow = t >> 3;
  const int ssw = ((t & 7) * 16) ^ ((srow & 7) << 4);
  const u16* kb0 = kws + ((size_t)bh * 2048 + srow) * 64 + (ssw >> 1);
  const u16* vb0 = vtws + ((size_t)bh * 64 + srow) * 2048 + (ssw >> 1);

#define STAGE(kv0, buf)                                                \
  do {                                                                 \
    async_copy16(&Ksh[buf][t * 8],          kb0 + (size_t)(kv0)*64);   \
    async_copy16(&Ksh[buf][(t + 256) * 8],  kb0 + (size_t)((kv0)+32)*64); \
    async_copy16(&VTsh[buf][t * 8],         vb0 + (kv0));              \
    async_copy16(&VTsh[buf][(t + 256) * 8], vb0 + (size_t)32*2048 + (kv0)); \
  } while (0)

  const int nt = (qtile + 1) * 2;
  STAGE(0, 0);

  for (int ti = 0; ti < nt; ++ti) {
    const int kv0 = ti * 64;
    const int cur = ti & 1;
    if (ti + 1 < nt) {
      STAGE((ti + 1) * 64, cur ^ 1);
      asm volatile("s_waitcnt vmcnt(4)" ::: "memory");  // tile ti retired
    } else {
      asm volatile("s_waitcnt vmcnt(0)" ::: "memory");
    }
    __builtin_amdgcn_sched_barrier(0);
    asm volatile("s_barrier" ::: "memory");  // tile ti visible to all waves

    if (kv0 <= q0 + 31) {
      const u16* Kc = Ksh[cur];
      const u16* Vc = VTsh[cur];

      f32x16 st[2] = {};
      __builtin_amdgcn_s_setprio(1);
#pragma unroll
      for (int kt = 0; kt < 2; ++kt) {
        const int krow = kt * 32 + lq;
        const int swz = (krow & 7) << 4;
#pragma unroll
        for (int s = 0; s < 4; ++s) {
          bf16x8 kf = *(const bf16x8*)&Kc[krow * 64 + (((s * 32 + h * 16) ^ swz) >> 1)];
          st[kt] = MFMA32(kf, qf[s], st[kt]);
        }
      }
      __builtin_amdgcn_s_setprio(0);

      const bool diag = (kv0 + 63 > q0);
#pragma unroll
      for (int kt = 0; kt < 2; ++kt)
#pragma unroll
        for (int p = 0; p < 16; ++p) {
          float e = exp2f(st[kt][p]);  // Q pre-scaled by 0.125*log2e
          if (diag) {
            const int key = kv0 + kt * 32 + (p & 3) + 8 * (p >> 2) + 4 * h;
            e = (key <= qg) ? e : 0.f;
          }
          st[kt][p] = e;
          lsv[p & 3] += e;  // static index (p compile-time) -> register
        }

      bf16x8 pb[4];
#pragma unroll
      for (int kt = 0; kt < 2; ++kt)
#pragma unroll
        for (int s2l = 0; s2l < 2; ++s2l) {
          const int p0 = s2l * 8;
          u32 L0 = pk_bf16(st[kt][p0 + 0], st[kt][p0 + 1]);
          u32 L1 = pk_bf16(st[kt][p0 + 2], st[kt][p0 + 3]);
          u32 H0 = pk_bf16(st[kt][p0 + 4], st[kt][p0 + 5]);
          u32 H1 = pk_bf16(st[kt][p0 + 6], st[kt][p0 + 7]);
          PLSWAP(L0, H0);
          PLSWAP(L1, H1);
          union { u32 u[4]; bf16x8 v; } pw;
          pw.u[0] = L0; pw.u[1] = L1; pw.u[2] = H0; pw.u[3] = H1;
          pb[kt * 2 + s2l] = pw.v;
        }

      __builtin_amdgcn_s_setprio(1);
#pragma unroll
      for (int dt = 0; dt < 2; ++dt) {
        const int vrow = dt * 32 + lq;
        const int swz = (vrow & 7) << 4;
#pragma unroll
        for (int s2 = 0; s2 < 4; ++s2) {
          bf16x8 vf = *(const bf16x8*)&Vc[vrow * 64 + (((s2 * 32 + h * 16) ^ swz) >> 1)];
          oacc[dt] = MFMA32(vf, pb[s2], oacc[dt]);
        }
      }
      __builtin_amdgcn_s_setprio(0);
    }
    asm volatile("s_barrier" ::: "memory");  // reads(cur) done before overwrite
  }
#undef STAGE

  float lsum = (lsv[0] + lsv[1]) + (lsv[2] + lsv[3]);
  lsum += __shfl_xor(lsum, 32, 64);
  const float linv = 1.f / lsum;

  const int b = bh >> 4, hh = bh & 15;
  u16* yb = ybf + ((size_t)b * 2048 + qg) * 1024 + hh * 64;
#pragma unroll
  for (int dt = 0; dt < 2; ++dt)
#pragma unroll
    for (int pg = 0; pg < 4; ++pg) {
      u32 w0 = pk_bf16(oacc[dt][pg * 4 + 0] * linv, oacc[dt][pg * 4 + 1] * linv);
      u32 w1 = pk_bf16(oacc[dt][pg * 4 + 2] * linv, oacc[dt][pg * 4 + 3] * linv);
      union { u32 u[2]; unsigned long long ll; } pk2;
      pk2.u[0] = w0; pk2.u[1] = w1;
      *(unsigned long long*)(yb + dt * 32 + 8 * pg + 4 * h) = pk2.ll;
    }
}

// ---------- launch ----------
extern "C" void kernel_launch(void* const* d_in, const int* in_sizes, int n_in,
                              void* d_out, int out_size, void* d_ws, size_t ws_size,
                              hipStream_t stream) {
  const float* x     = (const float*)d_in[0];   // [4,2048,1024]
  const float* wqkv  = (const float*)d_in[1];   // [1024,3072]
  const float* wproj = (const float*)d_in[2];   // [1024,1024]
  float* out = (float*)d_out;                   // [4,2048,1024] f32

  char* ws = (char*)d_ws;
  u16* xbf    = (u16*)ws;
  u16* ybf    = xbf;  // alias (x dead after qkv GEMM)
  u16* wqkvT  = (u16*)(ws + 16777216);
  u16* wprojT = (u16*)(ws + 16777216 + 6291456);
  u16* qws    = (u16*)(ws + 25165824);
  u16* kws    = (u16*)(ws + 41943040);
  u16* vtws   = (u16*)(ws + 58720256);

  prep_kernel<<<6144, 256, 0, stream>>>(x, wqkv, wproj, xbf, wqkvT, wprojT);
  gemm_cnt<0><<<dim3(64, 24), 256, 0, stream>>>(xbf, wqkvT, 1024, 3072, qws, kws, vtws, nullptr);
  attn_kernel<<<16 * 64, 256, 0, stream>>>(qws, kws, vtws, ybf);
  gemm_cnt<1><<<dim3(64, 8), 256, 0, stream>>>(ybf, wprojT, 1024, 1024, nullptr, nullptr, nullptr, out);
}